// Round 6
// baseline (678.836 us; speedup 1.0000x reference)
//
#include <hip/hip_runtime.h>
#include <math.h>

#define Bn   4
#define Tn   2048
#define Dn   1024
#define Hn   4
#define DKn  128
#define DVn  256
#define KDn  512
#define VDn  1024
#define NROWS 8192
#define NC   32
#define CLS  64
#define NCO  16
#define CLO  128
#define LOG_T_REF_F 6.2383246250395075f

using bf16x8 = __attribute__((ext_vector_type(8))) short;
using f32x4  = __attribute__((ext_vector_type(4))) float;
using f32x2  = __attribute__((ext_vector_type(2))) float;

__device__ __forceinline__ float softplus_f(float x) {
    return fmaxf(x, 0.0f) + log1pf(expf(-fabsf(x)));
}
__device__ __forceinline__ ushort f2bf(float f) {
    unsigned u = __float_as_uint(f);
    u = (u + 0x7fffu + ((u >> 16) & 1u)) >> 16;
    return (ushort)u;
}
__device__ __forceinline__ void gload16(const void* g, void* l) {
    __builtin_amdgcn_global_load_lds(
        (const __attribute__((address_space(1))) unsigned*)g,
        (__attribute__((address_space(3))) unsigned*)l, 16, 0, 0);
}

// ---------- cast fp32 -> bf16 ----------
__global__ __launch_bounds__(256) void cast_f2b(const float* __restrict__ x,
                                                ushort* __restrict__ y, int n4) {
    int i = blockIdx.x * 256 + threadIdx.x;
    if (i < n4) {
        float4 v = *(const float4*)&x[i * 4];
        ushort4 o;
        o.x = f2bf(v.x); o.y = f2bf(v.y); o.z = f2bf(v.z); o.w = f2bf(v.w);
        *(ushort4*)&y[i * 4] = o;
    }
}

// ---------- bf16 MFMA GEMM, global_load_lds staging, XCD-swizzled 1-D grid ----------
// A[M x 1024] @ Bw[NX*128 x 1024]^T, fp32 accumulate. Grid = NX*64 blocks (multiple of 8).
// MODE 0: plain fp32 -> C [.][1024]
// MODE 1 (qka, NX=12): cols<512 scaled fp32 -> C; 512..1023 fp32 -> C; >=1024 gate -> Eo [.][512]
// MODE 2 (vg,  NX=16): cols<1024 fp32 -> C (v); >=1024 -> bf16 C2 (g)
template<int MODE, int NX>
__global__ __launch_bounds__(256) void mm2(const ushort* __restrict__ A,
    const ushort* __restrict__ Bw, float* __restrict__ C,
    ushort* __restrict__ C2, float* __restrict__ Eo,
    const float* __restrict__ dt_bias, const float* __restrict__ A_log_base,
    const float* __restrict__ A_log_delta)
{
    __shared__ __align__(16) ushort As[4][128][8];   // [kslot(8 bf16)][row][8]
    __shared__ __align__(16) ushort Bs[4][128][8];
    const int raw = blockIdx.x;
    const int nwg = NX * 64;
    const int l = (raw & 7) * (nwg >> 3) + (raw >> 3);   // XCD-chunked remap
    const int bx = l % NX, by = l / NX;
    const int tid = threadIdx.x;
    const int lane = tid & 63, w = tid >> 6;
    const int l15 = lane & 15, lg = lane >> 4;
    const int wr = (w >> 1) << 6, wc = (w & 1) << 6;
    const int row0 = by << 7, col0 = bx << 7;

    const ushort* Ag0 = A  + (size_t)(row0 + lane) * Dn + w * 8;
    const ushort* Ag1 = A  + (size_t)(row0 + 64 + lane) * Dn + w * 8;
    const ushort* Bg0 = Bw + (size_t)(col0 + lane) * Dn + w * 8;
    const ushort* Bg1 = Bw + (size_t)(col0 + 64 + lane) * Dn + w * 8;
    ushort* lA0 = &As[w][0][0];
    ushort* lA1 = &As[w][64][0];
    ushort* lB0 = &Bs[w][0][0];
    ushort* lB1 = &Bs[w][64][0];

    f32x4 acc[4][4];
    #pragma unroll
    for (int m = 0; m < 4; ++m)
        #pragma unroll
        for (int n = 0; n < 4; ++n)
            acc[m][n] = (f32x4){0.f, 0.f, 0.f, 0.f};

    for (int kt = 0; kt < Dn; kt += 32) {
        __syncthreads();
        gload16(Ag0 + kt, lA0);
        gload16(Ag1 + kt, lA1);
        gload16(Bg0 + kt, lB0);
        gload16(Bg1 + kt, lB1);
        __syncthreads();
        bf16x8 af[4], bv[4];
        #pragma unroll
        for (int m = 0; m < 4; ++m) af[m] = *(const bf16x8*)&As[lg][wr + m*16 + l15][0];
        #pragma unroll
        for (int n = 0; n < 4; ++n) bv[n] = *(const bf16x8*)&Bs[lg][wc + n*16 + l15][0];
        #pragma unroll
        for (int m = 0; m < 4; ++m)
            #pragma unroll
            for (int n = 0; n < 4; ++n)
                acc[m][n] = __builtin_amdgcn_mfma_f32_16x16x32_bf16(af[m], bv[n], acc[m][n], 0, 0, 0);
    }

    if (MODE == 1 && col0 >= 1024) {
        const float base_ = A_log_base[0];
        const float s0 = softplus_f(A_log_delta[0]);
        const float s1 = softplus_f(A_log_delta[1]);
        const float s2 = softplus_f(A_log_delta[2]);
        const float c3 = s0 + s1 + s2;
        const float mg = c3 * (1.0f / 3.0f);
        float pf[4][4];
        #pragma unroll
        for (int m = 0; m < 4; ++m) {
            const int row = row0 + wr + m * 16 + lg * 4;
            #pragma unroll
            for (int r = 0; r < 4; ++r) {
                const int t = (row + r) & (Tn - 1);
                pf[m][r] = logf((float)(t + 1));
            }
        }
        #pragma unroll
        for (int n = 0; n < 4; ++n) {
            const int dk = col0 - 1024 + wc + n * 16 + l15;   // 0..511
            const int h = dk >> 7;
            const float cumh = (h == 0) ? 0.f : (h == 1) ? s0 : (h == 2) ? s0 + s1 : c3;
            float alpha = (float)(3 - h) * (1.0f / 3.0f)
                        + (cumh - (float)h * mg) * (1.0f / LOG_T_REF_F);
            alpha = fminf(fmaxf(alpha, 0.0f), 1.0f);
            const float expA = expf(base_ + cumh);
            const float db = dt_bias[dk];
            #pragma unroll
            for (int m = 0; m < 4; ++m) {
                const int row = row0 + wr + m * 16 + lg * 4;
                #pragma unroll
                for (int r = 0; r < 4; ++r) {
                    const float p = expf(-alpha * pf[m][r]);
                    Eo[(size_t)(row + r) * KDn + dk] =
                        expf(-expA * softplus_f(acc[m][n][r] + db) * p);
                }
            }
        }
    } else if (MODE == 2 && col0 >= 1024) {
        #pragma unroll
        for (int m = 0; m < 4; ++m) {
            const int row = row0 + wr + m * 16 + lg * 4;
            #pragma unroll
            for (int n = 0; n < 4; ++n) {
                const int col = col0 - 1024 + wc + n * 16 + l15;
                #pragma unroll
                for (int r = 0; r < 4; ++r)
                    C2[(size_t)(row + r) * 1024 + col] = f2bf(acc[m][n][r]);
            }
        }
    } else {
        const float s = (MODE == 1 && col0 < 512) ? 0.08838834764831845f : 1.0f;
        #pragma unroll
        for (int m = 0; m < 4; ++m) {
            const int row = row0 + wr + m * 16 + lg * 4;
            #pragma unroll
            for (int n = 0; n < 4; ++n) {
                const int col = col0 + wc + n * 16 + l15;
                #pragma unroll
                for (int r = 0; r < 4; ++r)
                    C[(size_t)(row + r) * 1024 + col] = acc[m][n][r] * s;
            }
        }
    }
}

// ---------- chunked GLA recurrence ----------
// qk: [8192][1024] fp32 (q 0-511 pre-scaled | k 512-1023). vb: [8192][1024] fp32.
// E: [8192][512] fp32.
// Thread (part=tid&15, dvi=tid>>4): dk pairs i=0..3 -> {p*4,p*4+1},{p*4+2,p*4+3},
// {64+p*4,+1},{64+p*4+2,+3}; dv = dvb*32 + dvi*2 (+j, j=0,1).
// dk comes PACKED from float4 loads (no splats); v is splat (2 movs).

// local states at fine chunks (NC=32 x 64). Grid 4096, XCD-swizzled, 8 blocks/CU.
__global__ __launch_bounds__(256, 8) void gla_state(const float* __restrict__ qk,
    const float* __restrict__ E, const float* __restrict__ vb, float* __restrict__ Sl)
{
    const int raw = blockIdx.x;
    const int l = (raw & 7) * 512 + (raw >> 3);
    const int dvb = l & 7, bh = (l >> 3) & 15, c = l >> 7;   // c: 0..31
    const int tid = threadIdx.x;
    const int part = tid & 15, dvi = tid >> 4;
    const int b = bh >> 2, h = bh & 3;
    const int t0 = c * CLS;
    const int dv = dvb * 32 + dvi * 2;
    int ko = (b * Tn + t0) * 1024 + 512 + h * DKn + part * 4;
    int eo = (b * Tn + t0) * KDn + h * DKn + part * 4;
    int vo = (b * Tn + t0) * 1024 + h * DVn + dv;

    f32x2 S[4][2];
    #pragma unroll
    for (int i = 0; i < 4; ++i) { S[i][0] = (f32x2){0.f,0.f}; S[i][1] = (f32x2){0.f,0.f}; }

    #pragma unroll 2
    for (int t = 0; t < CLS; ++t) {
        float4 kA = *(const float4*)(qk + ko);
        float4 kB = *(const float4*)(qk + ko + 64);
        float4 eA = *(const float4*)(E + eo);
        float4 eB = *(const float4*)(E + eo + 64);
        float2 vv = *(const float2*)(vb + vo);
        ko += 1024; eo += KDn; vo += 1024;
        f32x2 k2[4] = {{kA.x,kA.y},{kA.z,kA.w},{kB.x,kB.y},{kB.z,kB.w}};
        f32x2 e2[4] = {{eA.x,eA.y},{eA.z,eA.w},{eB.x,eB.y},{eB.z,eB.w}};
        const f32x2 vs0 = (f32x2){vv.x, vv.x};
        const f32x2 vs1 = (f32x2){vv.y, vv.y};
        #pragma unroll
        for (int i = 0; i < 4; ++i) {
            S[i][0] = S[i][0] * e2[i] + k2[i] * vs0;
            S[i][1] = S[i][1] * e2[i] + k2[i] * vs1;
        }
    }
    float* sp = Sl + (((size_t)c * 16 + bh) << 15);
    #pragma unroll
    for (int i = 0; i < 4; ++i) {
        const int dke = (i < 2) ? part * 4 + i * 2 : 64 + part * 4 + (i - 2) * 2;
        *(float2*)&sp[(dke + 0) * DVn + dv] = make_float2(S[i][0].x, S[i][1].x);
        *(float2*)&sp[(dke + 1) * DVn + dv] = make_float2(S[i][0].y, S[i][1].y);
    }
}

__global__ void decay_prod(const float* __restrict__ E, float* __restrict__ Dc) {
    const int dk = threadIdx.x;           // 0..127
    const int c = blockIdx.x, bh = blockIdx.y;
    const int b = bh >> 2, h = bh & 3;
    const float* Ep = E + (size_t)(b * Tn + c * CLS) * KDn + h * DKn + dk;
    float p = 1.f;
    for (int t = 0; t < CLS; ++t) { p *= *Ep; Ep += KDn; }
    Dc[(c * 16 + bh) * DKn + dk] = p;
}

// sequential chunk combine: overwrite Sl[c] with chunk-c START state
__global__ __launch_bounds__(256) void combine(float* __restrict__ Sl,
                                               const float* __restrict__ Dc) {
    const int bh = blockIdx.y;
    const int e4 = blockIdx.x * 256 + threadIdx.x;   // 0..8191 float4 per state
    const int dk = e4 >> 6;
    float4 s = make_float4(0.f, 0.f, 0.f, 0.f);
    #pragma unroll 4
    for (int c = 0; c < NC; ++c) {
        float4* p = (float4*)(Sl + (((size_t)c * 16 + bh) << 15)) + e4;
        float4 local = *p;
        const float d = Dc[(c * 16 + bh) * DKn + dk];
        *p = s;
        s.x = s.x * d + local.x;  s.y = s.y * d + local.y;
        s.z = s.z * d + local.z;  s.w = s.w * d + local.w;
    }
}

// output pass at coarse chunks (NCO=16 x 128), start state = Sl[2*co].
// Grid 2048, XCD-swizzled, 8 blocks/CU. dv = dvb*32 + dvi*2.
__global__ __launch_bounds__(256, 8) void gla_out(const float* __restrict__ qk,
    const float* __restrict__ E, const float* __restrict__ vb,
    const float* __restrict__ Sl, float* __restrict__ o)
{
    const int raw = blockIdx.x;
    const int l = (raw & 7) * 256 + (raw >> 3);
    const int dvb = l & 7, bh = (l >> 3) & 15, co = l >> 7;  // co: 0..15
    const int tid = threadIdx.x;
    const int part = tid & 15, dvi = tid >> 4;
    const int b = bh >> 2, h = bh & 3;
    const int t0 = co * CLO;
    const int dv = dvb * 32 + dvi * 2;
    int qo = (b * Tn + t0) * 1024 + h * DKn + part * 4;
    int eo = (b * Tn + t0) * KDn + h * DKn + part * 4;
    int vo = (b * Tn + t0) * 1024 + h * DVn + dv;
    int oo = vo;

    const float* sp = Sl + (((size_t)(2 * co) * 16 + bh) << 15);
    f32x2 S[4][2];
    #pragma unroll
    for (int i = 0; i < 4; ++i) {
        const int dke = (i < 2) ? part * 4 + i * 2 : 64 + part * 4 + (i - 2) * 2;
        float2 a = *(const float2*)&sp[(dke + 0) * DVn + dv];
        float2 bq = *(const float2*)&sp[(dke + 1) * DVn + dv];
        S[i][0] = (f32x2){a.x, bq.x};
        S[i][1] = (f32x2){a.y, bq.y};
    }

    #pragma unroll 2
    for (int t = 0; t < CLO; ++t) {
        float4 qA = *(const float4*)(qk + qo);
        float4 qB = *(const float4*)(qk + qo + 64);
        float4 kA = *(const float4*)(qk + qo + 512);
        float4 kB = *(const float4*)(qk + qo + 576);
        float4 eA = *(const float4*)(E + eo);
        float4 eB = *(const float4*)(E + eo + 64);
        float2 vv = *(const float2*)(vb + vo);
        qo += 1024; eo += KDn; vo += 1024;
        f32x2 q2[4] = {{qA.x,qA.y},{qA.z,qA.w},{qB.x,qB.y},{qB.z,qB.w}};
        f32x2 k2[4] = {{kA.x,kA.y},{kA.z,kA.w},{kB.x,kB.y},{kB.z,kB.w}};
        f32x2 e2[4] = {{eA.x,eA.y},{eA.z,eA.w},{eB.x,eB.y},{eB.z,eB.w}};
        const f32x2 vs0 = (f32x2){vv.x, vv.x};
        const f32x2 vs1 = (f32x2){vv.y, vv.y};
        f32x2 p0 = (f32x2){0.f,0.f}, p1 = (f32x2){0.f,0.f};
        #pragma unroll
        for (int i = 0; i < 4; ++i) {
            S[i][0] = S[i][0] * e2[i] + k2[i] * vs0;
            p0 = p0 + q2[i] * S[i][0];
            S[i][1] = S[i][1] * e2[i] + k2[i] * vs1;
            p1 = p1 + q2[i] * S[i][1];
        }
        // horizontal (dk even+odd), then 16-part butterfly as one packed 64-bit shfl
        f32x2 pp = (f32x2){p0.x + p0.y, p1.x + p1.y};
        #pragma unroll
        for (int m = 1; m < 16; m <<= 1) {
            long long x = __shfl_xor(*(long long*)&pp, m);
            pp = pp + *(f32x2*)&x;
        }
        if (part == 0) *(float2*)(o + oo) = make_float2(pp.x, pp.y);
        oo += 1024;
    }
}

// ---------- RMSNorm + swish gate (g in bf16) -> bf16 ----------
__global__ __launch_bounds__(256) void rms_gate(const float* __restrict__ o,
    const ushort* __restrict__ gbf, const float* __restrict__ wt,
    ushort* __restrict__ obf)
{
    const int tid = threadIdx.x;
    const int w = tid >> 6, lane = tid & 63;
    const int row = blockIdx.x * 4 + w;     // n*H + h
    const int n = row >> 2, h = row & 3;
    const size_t ob_base = (size_t)n * VDn + h * DVn + lane * 4;

    float4 o4 = *(const float4*)&o[ob_base];
    float ss = o4.x*o4.x + o4.y*o4.y + o4.z*o4.z + o4.w*o4.w;
    #pragma unroll
    for (int m = 1; m < 64; m <<= 1) ss += __shfl_xor(ss, m);
    const float r = rsqrtf(ss * (1.0f / DVn) + 1e-5f);

    ushort4 gu = *(const ushort4*)&gbf[ob_base];
    float gx = __uint_as_float((unsigned)gu.x << 16);
    float gy = __uint_as_float((unsigned)gu.y << 16);
    float gz = __uint_as_float((unsigned)gu.z << 16);
    float gw = __uint_as_float((unsigned)gu.w << 16);
    float4 w4 = *(const float4*)&wt[h * DVn + lane * 4];
    ushort4 u;
    u.x = f2bf(o4.x * r * w4.x * (gx / (1.0f + expf(-gx))));
    u.y = f2bf(o4.y * r * w4.y * (gy / (1.0f + expf(-gy))));
    u.z = f2bf(o4.z * r * w4.z * (gz / (1.0f + expf(-gz))));
    u.w = f2bf(o4.w * r * w4.w * (gw / (1.0f + expf(-gw))));
    *(ushort4*)&obf[ob_base] = u;
}

extern "C" void kernel_launch(void* const* d_in, const int* in_sizes, int n_in,
                              void* d_out, int out_size, void* d_ws, size_t ws_size,
                              hipStream_t stream) {
    const float* hs          = (const float*)d_in[0];
    const float* Wq          = (const float*)d_in[1];
    const float* Wk          = (const float*)d_in[2];
    const float* Wv          = (const float*)d_in[3];
    const float* Wg          = (const float*)d_in[4];
    const float* Wa          = (const float*)d_in[5];
    const float* Wo          = (const float*)d_in[6];
    const float* A_log_base  = (const float*)d_in[7];
    const float* A_log_delta = (const float*)d_in[8];
    const float* dt_bias     = (const float*)d_in[9];
    const float* gnw         = (const float*)d_in[10];
    float* out = (float*)d_out;

    char* ws = (char*)d_ws;
    float*  qk   = (float*)(ws);                           // 32MB [8192][1024] q|k
    float*  vb   = (float*)(ws + ((size_t)32  << 20));     // 32MB [8192][1024] v fp32
    float*  Eb   = (float*)(ws + ((size_t)64  << 20));     // 16MB [8192][512]
    float*  Sl   = (float*)(ws + ((size_t)80  << 20));     // 64MB [32][16][128][256]
    float*  ob   = (float*)(ws + ((size_t)144 << 20));     // 32MB [8192][1024]
    ushort* hsb  = (ushort*)(ws + ((size_t)144 << 20));    // 16MB overlay on ob (dead before gla_out)
    ushort* gbf  = (ushort*)(ws + ((size_t)176 << 20));    // 16MB [8192][1024] g bf16
    ushort* Wqkab= (ushort*)(ws + ((size_t)192 << 20));    //  3MB [1536][1024] bf16
    ushort* Wvgb = (ushort*)(ws + ((size_t)195 << 20));    //  4MB [2048][1024] bf16
    ushort* Wob  = (ushort*)(ws + ((size_t)199 << 20));    //  2MB [1024][1024] bf16
    float*  Dc   = (float*)(ws + ((size_t)201 << 20));     // 256KB [32][16][128]
    ushort* obf  = (ushort*)qk;                            // reuse qk after gla_out

    // casts
    cast_f2b<<<NROWS * Dn / 4 / 256, 256, 0, stream>>>(hs, hsb, NROWS * Dn / 4);
    cast_f2b<<<512,  256, 0, stream>>>(Wq, Wqkab,              KDn * Dn / 4);
    cast_f2b<<<512,  256, 0, stream>>>(Wk, Wqkab + KDn * Dn,   KDn * Dn / 4);
    cast_f2b<<<512,  256, 0, stream>>>(Wa, Wqkab + 2*KDn * Dn, KDn * Dn / 4);
    cast_f2b<<<1024, 256, 0, stream>>>(Wv, Wvgb,               VDn * Dn / 4);
    cast_f2b<<<1024, 256, 0, stream>>>(Wg, Wvgb + VDn * Dn,    VDn * Dn / 4);
    cast_f2b<<<1024, 256, 0, stream>>>(Wo, Wob,                VDn * Dn / 4);

    // projections: q|k (scaled q) + fused gate transform -> Eb ; v fp32 + g bf16
    mm2<1,12><<<768,  256, 0, stream>>>(hsb, Wqkab, qk, nullptr, Eb,
                                        dt_bias, A_log_base, A_log_delta);
    mm2<2,16><<<1024, 256, 0, stream>>>(hsb, Wvgb, vb, gbf, nullptr,
                                        nullptr, nullptr, nullptr);

    // chunked recurrence: fine chunks for state (NC=32), coarse for output (16)
    gla_state<<<4096, 256, 0, stream>>>(qk, Eb, vb, Sl);
    decay_prod<<<dim3(NC, 16), 128, 0, stream>>>(Eb, Dc);
    combine<<<dim3(32, 16), 256, 0, stream>>>(Sl, Dc);
    gla_out<<<2048, 256, 0, stream>>>(qk, Eb, vb, Sl, ob);

    // epilogue
    rms_gate<<<NROWS * Hn / 4, 256, 0, stream>>>(ob, gbf, gnw, obf);
    mm2<0,8><<<512, 256, 0, stream>>>(obf, Wob, out, nullptr, nullptr,
                                      nullptr, nullptr, nullptr);
}

// Round 7
// 673.137 us; speedup vs baseline: 1.0085x; 1.0085x over previous
//
#include <hip/hip_runtime.h>
#include <math.h>

#define Bn   4
#define Tn   2048
#define Dn   1024
#define Hn   4
#define DKn  128
#define DVn  256
#define KDn  512
#define VDn  1024
#define NROWS 8192
#define NC   32
#define CLS  64
#define NCO  16
#define CLO  128
#define LOG_T_REF_F 6.2383246250395075f

using bf16x8 = __attribute__((ext_vector_type(8))) short;
using f32x4  = __attribute__((ext_vector_type(4))) float;
using f32x2  = __attribute__((ext_vector_type(2))) float;

__device__ __forceinline__ float softplus_f(float x) {
    return fmaxf(x, 0.0f) + log1pf(expf(-fabsf(x)));
}
__device__ __forceinline__ ushort f2bf(float f) {
    unsigned u = __float_as_uint(f);
    u = (u + 0x7fffu + ((u >> 16) & 1u)) >> 16;
    return (ushort)u;
}
__device__ __forceinline__ void gload16(const void* g, void* l) {
    __builtin_amdgcn_global_load_lds(
        (const __attribute__((address_space(1))) unsigned*)g,
        (__attribute__((address_space(3))) unsigned*)l, 16, 0, 0);
}
// packed full-sum butterfly over each aligned 16-lane group, pure VALU (DPP)
__device__ __forceinline__ f32x2 dpp_red16_x2(f32x2 p) {
    f32x2 t;
#define RSTEP(ctl)                                                                              \
    t.x = __int_as_float(__builtin_amdgcn_mov_dpp(__float_as_int(p.x), ctl, 0xF, 0xF, true));   \
    t.y = __int_as_float(__builtin_amdgcn_mov_dpp(__float_as_int(p.y), ctl, 0xF, 0xF, true));   \
    p = p + t;
    RSTEP(0xB1)   // quad_perm xor1
    RSTEP(0x4E)   // quad_perm xor2
    RSTEP(0x124)  // row_ror:4
    RSTEP(0x128)  // row_ror:8
#undef RSTEP
    return p;
}

// ---------- cast fp32 -> bf16 ----------
__global__ __launch_bounds__(256) void cast_f2b(const float* __restrict__ x,
                                                ushort* __restrict__ y, int n4) {
    int i = blockIdx.x * 256 + threadIdx.x;
    if (i < n4) {
        float4 v = *(const float4*)&x[i * 4];
        ushort4 o;
        o.x = f2bf(v.x); o.y = f2bf(v.y); o.z = f2bf(v.z); o.w = f2bf(v.w);
        *(ushort4*)&y[i * 4] = o;
    }
}

// ---------- bf16 MFMA GEMM, global_load_lds staging, XCD-swizzled 1-D grid ----------
// A[M x 1024] @ Bw[NX*128 x 1024]^T, fp32 accumulate. Grid = NX*64 blocks (multiple of 8).
// MODE 0: plain fp32 -> C [.][1024]
// MODE 1 (qka, NX=12): cols<512 scaled fp32 -> C; 512..1023 fp32 -> C; >=1024 gate -> Eo [.][512]
// MODE 2 (vg,  NX=16): cols<1024 fp32 -> C (v); >=1024 -> bf16 C2 (g)
template<int MODE, int NX>
__global__ __launch_bounds__(256) void mm2(const ushort* __restrict__ A,
    const ushort* __restrict__ Bw, float* __restrict__ C,
    ushort* __restrict__ C2, float* __restrict__ Eo,
    const float* __restrict__ dt_bias, const float* __restrict__ A_log_base,
    const float* __restrict__ A_log_delta)
{
    __shared__ __align__(16) ushort As[4][128][8];   // [kslot(8 bf16)][row][8]
    __shared__ __align__(16) ushort Bs[4][128][8];
    const int raw = blockIdx.x;
    const int nwg = NX * 64;
    const int l = (raw & 7) * (nwg >> 3) + (raw >> 3);   // XCD-chunked remap
    const int bx = l % NX, by = l / NX;
    const int tid = threadIdx.x;
    const int lane = tid & 63, w = tid >> 6;
    const int l15 = lane & 15, lg = lane >> 4;
    const int wr = (w >> 1) << 6, wc = (w & 1) << 6;
    const int row0 = by << 7, col0 = bx << 7;

    const ushort* Ag0 = A  + (size_t)(row0 + lane) * Dn + w * 8;
    const ushort* Ag1 = A  + (size_t)(row0 + 64 + lane) * Dn + w * 8;
    const ushort* Bg0 = Bw + (size_t)(col0 + lane) * Dn + w * 8;
    const ushort* Bg1 = Bw + (size_t)(col0 + 64 + lane) * Dn + w * 8;
    ushort* lA0 = &As[w][0][0];
    ushort* lA1 = &As[w][64][0];
    ushort* lB0 = &Bs[w][0][0];
    ushort* lB1 = &Bs[w][64][0];

    f32x4 acc[4][4];
    #pragma unroll
    for (int m = 0; m < 4; ++m)
        #pragma unroll
        for (int n = 0; n < 4; ++n)
            acc[m][n] = (f32x4){0.f, 0.f, 0.f, 0.f};

    for (int kt = 0; kt < Dn; kt += 32) {
        __syncthreads();
        gload16(Ag0 + kt, lA0);
        gload16(Ag1 + kt, lA1);
        gload16(Bg0 + kt, lB0);
        gload16(Bg1 + kt, lB1);
        __syncthreads();
        bf16x8 af[4], bv[4];
        #pragma unroll
        for (int m = 0; m < 4; ++m) af[m] = *(const bf16x8*)&As[lg][wr + m*16 + l15][0];
        #pragma unroll
        for (int n = 0; n < 4; ++n) bv[n] = *(const bf16x8*)&Bs[lg][wc + n*16 + l15][0];
        #pragma unroll
        for (int m = 0; m < 4; ++m)
            #pragma unroll
            for (int n = 0; n < 4; ++n)
                acc[m][n] = __builtin_amdgcn_mfma_f32_16x16x32_bf16(af[m], bv[n], acc[m][n], 0, 0, 0);
    }

    if (MODE == 1 && col0 >= 1024) {
        const float base_ = A_log_base[0];
        const float s0 = softplus_f(A_log_delta[0]);
        const float s1 = softplus_f(A_log_delta[1]);
        const float s2 = softplus_f(A_log_delta[2]);
        const float c3 = s0 + s1 + s2;
        const float mg = c3 * (1.0f / 3.0f);
        float pf[4][4];
        #pragma unroll
        for (int m = 0; m < 4; ++m) {
            const int row = row0 + wr + m * 16 + lg * 4;
            #pragma unroll
            for (int r = 0; r < 4; ++r) {
                const int t = (row + r) & (Tn - 1);
                pf[m][r] = logf((float)(t + 1));
            }
        }
        #pragma unroll
        for (int n = 0; n < 4; ++n) {
            const int dk = col0 - 1024 + wc + n * 16 + l15;   // 0..511
            const int h = dk >> 7;
            const float cumh = (h == 0) ? 0.f : (h == 1) ? s0 : (h == 2) ? s0 + s1 : c3;
            float alpha = (float)(3 - h) * (1.0f / 3.0f)
                        + (cumh - (float)h * mg) * (1.0f / LOG_T_REF_F);
            alpha = fminf(fmaxf(alpha, 0.0f), 1.0f);
            const float expA = expf(base_ + cumh);
            const float db = dt_bias[dk];
            #pragma unroll
            for (int m = 0; m < 4; ++m) {
                const int row = row0 + wr + m * 16 + lg * 4;
                #pragma unroll
                for (int r = 0; r < 4; ++r) {
                    const float p = expf(-alpha * pf[m][r]);
                    Eo[(size_t)(row + r) * KDn + dk] =
                        expf(-expA * softplus_f(acc[m][n][r] + db) * p);
                }
            }
        }
    } else if (MODE == 2 && col0 >= 1024) {
        #pragma unroll
        for (int m = 0; m < 4; ++m) {
            const int row = row0 + wr + m * 16 + lg * 4;
            #pragma unroll
            for (int n = 0; n < 4; ++n) {
                const int col = col0 - 1024 + wc + n * 16 + l15;
                #pragma unroll
                for (int r = 0; r < 4; ++r)
                    C2[(size_t)(row + r) * 1024 + col] = f2bf(acc[m][n][r]);
            }
        }
    } else {
        const float s = (MODE == 1 && col0 < 512) ? 0.08838834764831845f : 1.0f;
        #pragma unroll
        for (int m = 0; m < 4; ++m) {
            const int row = row0 + wr + m * 16 + lg * 4;
            #pragma unroll
            for (int n = 0; n < 4; ++n) {
                const int col = col0 + wc + n * 16 + l15;
                #pragma unroll
                for (int r = 0; r < 4; ++r)
                    C[(size_t)(row + r) * 1024 + col] = acc[m][n][r] * s;
            }
        }
    }
}

// ---------- chunked GLA recurrence ----------
// qk: [8192][1024] fp32 (q 0-511 pre-scaled | k 512-1023). vb: [8192][1024] fp32.
// E: [8192][512] fp32.
// Thread (part=tid&15, dvi=tid>>4): dk pairs i=0..3 -> {p*4,p*4+1},{p*4+2,p*4+3},
// {64+p*4,+1},{64+p*4+2,+3}; dv = dvb*32 + dvi*2 (+j, j=0,1).
// dk comes PACKED from float4 loads (no splats); v is splat (2 movs).

// local states at fine chunks (NC=32 x 64). Grid 4096, XCD-swizzled, 8 blocks/CU.
// Also computes per-chunk decay product Dc (written by dvb==0, dvi==0 threads).
__global__ __launch_bounds__(256, 8) void gla_state(const float* __restrict__ qk,
    const float* __restrict__ E, const float* __restrict__ vb,
    float* __restrict__ Sl, float* __restrict__ Dc)
{
    const int raw = blockIdx.x;
    const int l = (raw & 7) * 512 + (raw >> 3);
    const int dvb = l & 7, bh = (l >> 3) & 15, c = l >> 7;   // c: 0..31
    const int tid = threadIdx.x;
    const int part = tid & 15, dvi = tid >> 4;
    const int b = bh >> 2, h = bh & 3;
    const int t0 = c * CLS;
    const int dv = dvb * 32 + dvi * 2;
    int ko = (b * Tn + t0) * 1024 + 512 + h * DKn + part * 4;
    int eo = (b * Tn + t0) * KDn + h * DKn + part * 4;
    int vo = (b * Tn + t0) * 1024 + h * DVn + dv;

    f32x2 S[4][2], P[4];
    #pragma unroll
    for (int i = 0; i < 4; ++i) {
        S[i][0] = (f32x2){0.f,0.f}; S[i][1] = (f32x2){0.f,0.f};
        P[i] = (f32x2){1.f,1.f};
    }

    #pragma unroll 2
    for (int t = 0; t < CLS; ++t) {
        float4 kA = *(const float4*)(qk + ko);
        float4 kB = *(const float4*)(qk + ko + 64);
        float4 eA = *(const float4*)(E + eo);
        float4 eB = *(const float4*)(E + eo + 64);
        float2 vv = *(const float2*)(vb + vo);
        ko += 1024; eo += KDn; vo += 1024;
        f32x2 k2[4] = {{kA.x,kA.y},{kA.z,kA.w},{kB.x,kB.y},{kB.z,kB.w}};
        f32x2 e2[4] = {{eA.x,eA.y},{eA.z,eA.w},{eB.x,eB.y},{eB.z,eB.w}};
        const f32x2 vs0 = (f32x2){vv.x, vv.x};
        const f32x2 vs1 = (f32x2){vv.y, vv.y};
        #pragma unroll
        for (int i = 0; i < 4; ++i) {
            S[i][0] = S[i][0] * e2[i] + k2[i] * vs0;
            S[i][1] = S[i][1] * e2[i] + k2[i] * vs1;
            P[i] = P[i] * e2[i];
        }
    }
    float* sp = Sl + (((size_t)c * 16 + bh) << 15);
    #pragma unroll
    for (int i = 0; i < 4; ++i) {
        const int dke = (i < 2) ? part * 4 + i * 2 : 64 + part * 4 + (i - 2) * 2;
        *(float2*)&sp[(dke + 0) * DVn + dv] = make_float2(S[i][0].x, S[i][1].x);
        *(float2*)&sp[(dke + 1) * DVn + dv] = make_float2(S[i][0].y, S[i][1].y);
    }
    if (dvb == 0 && dvi == 0) {
        float* dp = Dc + (c * 16 + bh) * DKn;
        #pragma unroll
        for (int i = 0; i < 4; ++i) {
            const int dke = (i < 2) ? part * 4 + i * 2 : 64 + part * 4 + (i - 2) * 2;
            *(float2*)&dp[dke] = make_float2(P[i].x, P[i].y);
        }
    }
}

// sequential chunk combine: overwrite Sl[c] with chunk-c START state
__global__ __launch_bounds__(256) void combine(float* __restrict__ Sl,
                                               const float* __restrict__ Dc) {
    const int bh = blockIdx.y;
    const int e4 = blockIdx.x * 256 + threadIdx.x;   // 0..8191 float4 per state
    const int dk = e4 >> 6;
    float4 s = make_float4(0.f, 0.f, 0.f, 0.f);
    #pragma unroll 4
    for (int c = 0; c < NC; ++c) {
        float4* p = (float4*)(Sl + (((size_t)c * 16 + bh) << 15)) + e4;
        float4 local = *p;
        const float d = Dc[(c * 16 + bh) * DKn + dk];
        *p = s;
        s.x = s.x * d + local.x;  s.y = s.y * d + local.y;
        s.z = s.z * d + local.z;  s.w = s.w * d + local.w;
    }
}

// output pass at coarse chunks (NCO=16 x 128), start state = Sl[2*co].
// Grid 2048, XCD-swizzled, 8 blocks/CU. dv = dvb*32 + dvi*2.
__global__ __launch_bounds__(256, 8) void gla_out(const float* __restrict__ qk,
    const float* __restrict__ E, const float* __restrict__ vb,
    const float* __restrict__ Sl, float* __restrict__ o)
{
    const int raw = blockIdx.x;
    const int l = (raw & 7) * 256 + (raw >> 3);
    const int dvb = l & 7, bh = (l >> 3) & 15, co = l >> 7;  // co: 0..15
    const int tid = threadIdx.x;
    const int part = tid & 15, dvi = tid >> 4;
    const int b = bh >> 2, h = bh & 3;
    const int t0 = co * CLO;
    const int dv = dvb * 32 + dvi * 2;
    int qo = (b * Tn + t0) * 1024 + h * DKn + part * 4;
    int eo = (b * Tn + t0) * KDn + h * DKn + part * 4;
    int vo = (b * Tn + t0) * 1024 + h * DVn + dv;
    int oo = vo;

    const float* sp = Sl + (((size_t)(2 * co) * 16 + bh) << 15);
    f32x2 S[4][2];
    #pragma unroll
    for (int i = 0; i < 4; ++i) {
        const int dke = (i < 2) ? part * 4 + i * 2 : 64 + part * 4 + (i - 2) * 2;
        float2 a = *(const float2*)&sp[(dke + 0) * DVn + dv];
        float2 bq = *(const float2*)&sp[(dke + 1) * DVn + dv];
        S[i][0] = (f32x2){a.x, bq.x};
        S[i][1] = (f32x2){a.y, bq.y};
    }

    #pragma unroll 2
    for (int t = 0; t < CLO; ++t) {
        float4 qA = *(const float4*)(qk + qo);
        float4 qB = *(const float4*)(qk + qo + 64);
        float4 kA = *(const float4*)(qk + qo + 512);
        float4 kB = *(const float4*)(qk + qo + 576);
        float4 eA = *(const float4*)(E + eo);
        float4 eB = *(const float4*)(E + eo + 64);
        float2 vv = *(const float2*)(vb + vo);
        qo += 1024; eo += KDn; vo += 1024;
        f32x2 q2[4] = {{qA.x,qA.y},{qA.z,qA.w},{qB.x,qB.y},{qB.z,qB.w}};
        f32x2 k2[4] = {{kA.x,kA.y},{kA.z,kA.w},{kB.x,kB.y},{kB.z,kB.w}};
        f32x2 e2[4] = {{eA.x,eA.y},{eA.z,eA.w},{eB.x,eB.y},{eB.z,eB.w}};
        const f32x2 vs0 = (f32x2){vv.x, vv.x};
        const f32x2 vs1 = (f32x2){vv.y, vv.y};
        f32x2 p0 = (f32x2){0.f,0.f}, p1 = (f32x2){0.f,0.f};
        #pragma unroll
        for (int i = 0; i < 4; ++i) {
            S[i][0] = S[i][0] * e2[i] + k2[i] * vs0;
            p0 = p0 + q2[i] * S[i][0];
            S[i][1] = S[i][1] * e2[i] + k2[i] * vs1;
            p1 = p1 + q2[i] * S[i][1];
        }
        // horizontal (dk even+odd) -> packed {dv, dv+1}, then pure-VALU DPP butterfly
        f32x2 pp = (f32x2){p0.x + p0.y, p1.x + p1.y};
        pp = dpp_red16_x2(pp);
        if (part == 0) *(float2*)(o + oo) = make_float2(pp.x, pp.y);
        oo += 1024;
    }
}

// ---------- RMSNorm + swish gate (g in bf16) -> bf16 ----------
__global__ __launch_bounds__(256) void rms_gate(const float* __restrict__ o,
    const ushort* __restrict__ gbf, const float* __restrict__ wt,
    ushort* __restrict__ obf)
{
    const int tid = threadIdx.x;
    const int w = tid >> 6, lane = tid & 63;
    const int row = blockIdx.x * 4 + w;     // n*H + h
    const int n = row >> 2, h = row & 3;
    const size_t ob_base = (size_t)n * VDn + h * DVn + lane * 4;

    float4 o4 = *(const float4*)&o[ob_base];
    float ss = o4.x*o4.x + o4.y*o4.y + o4.z*o4.z + o4.w*o4.w;
    #pragma unroll
    for (int m = 1; m < 64; m <<= 1) ss += __shfl_xor(ss, m);
    const float r = rsqrtf(ss * (1.0f / DVn) + 1e-5f);

    ushort4 gu = *(const ushort4*)&gbf[ob_base];
    float gx = __uint_as_float((unsigned)gu.x << 16);
    float gy = __uint_as_float((unsigned)gu.y << 16);
    float gz = __uint_as_float((unsigned)gu.z << 16);
    float gw = __uint_as_float((unsigned)gu.w << 16);
    float4 w4 = *(const float4*)&wt[h * DVn + lane * 4];
    ushort4 u;
    u.x = f2bf(o4.x * r * w4.x * (gx / (1.0f + expf(-gx))));
    u.y = f2bf(o4.y * r * w4.y * (gy / (1.0f + expf(-gy))));
    u.z = f2bf(o4.z * r * w4.z * (gz / (1.0f + expf(-gz))));
    u.w = f2bf(o4.w * r * w4.w * (gw / (1.0f + expf(-gw))));
    *(ushort4*)&obf[ob_base] = u;
}

extern "C" void kernel_launch(void* const* d_in, const int* in_sizes, int n_in,
                              void* d_out, int out_size, void* d_ws, size_t ws_size,
                              hipStream_t stream) {
    const float* hs          = (const float*)d_in[0];
    const float* Wq          = (const float*)d_in[1];
    const float* Wk          = (const float*)d_in[2];
    const float* Wv          = (const float*)d_in[3];
    const float* Wg          = (const float*)d_in[4];
    const float* Wa          = (const float*)d_in[5];
    const float* Wo          = (const float*)d_in[6];
    const float* A_log_base  = (const float*)d_in[7];
    const float* A_log_delta = (const float*)d_in[8];
    const float* dt_bias     = (const float*)d_in[9];
    const float* gnw         = (const float*)d_in[10];
    float* out = (float*)d_out;

    char* ws = (char*)d_ws;
    float*  qk   = (float*)(ws);                           // 32MB [8192][1024] q|k
    float*  vb   = (float*)(ws + ((size_t)32  << 20));     // 32MB [8192][1024] v fp32
    float*  Eb   = (float*)(ws + ((size_t)64  << 20));     // 16MB [8192][512]
    float*  Sl   = (float*)(ws + ((size_t)80  << 20));     // 64MB [32][16][128][256]
    float*  ob   = (float*)(ws + ((size_t)144 << 20));     // 32MB [8192][1024]
    ushort* hsb  = (ushort*)(ws + ((size_t)144 << 20));    // 16MB overlay on ob (dead before gla_out)
    ushort* gbf  = (ushort*)(ws + ((size_t)176 << 20));    // 16MB [8192][1024] g bf16
    ushort* Wqkab= (ushort*)(ws + ((size_t)192 << 20));    //  3MB [1536][1024] bf16
    ushort* Wvgb = (ushort*)(ws + ((size_t)195 << 20));    //  4MB [2048][1024] bf16
    ushort* Wob  = (ushort*)(ws + ((size_t)199 << 20));    //  2MB [1024][1024] bf16
    float*  Dc   = (float*)(ws + ((size_t)201 << 20));     // 256KB [32][16][128]
    ushort* obf  = (ushort*)qk;                            // reuse qk after gla_out

    // casts
    cast_f2b<<<NROWS * Dn / 4 / 256, 256, 0, stream>>>(hs, hsb, NROWS * Dn / 4);
    cast_f2b<<<512,  256, 0, stream>>>(Wq, Wqkab,              KDn * Dn / 4);
    cast_f2b<<<512,  256, 0, stream>>>(Wk, Wqkab + KDn * Dn,   KDn * Dn / 4);
    cast_f2b<<<512,  256, 0, stream>>>(Wa, Wqkab + 2*KDn * Dn, KDn * Dn / 4);
    cast_f2b<<<1024, 256, 0, stream>>>(Wv, Wvgb,               VDn * Dn / 4);
    cast_f2b<<<1024, 256, 0, stream>>>(Wg, Wvgb + VDn * Dn,    VDn * Dn / 4);
    cast_f2b<<<1024, 256, 0, stream>>>(Wo, Wob,                VDn * Dn / 4);

    // projections: q|k (scaled q) + fused gate transform -> Eb ; v fp32 + g bf16
    mm2<1,12><<<768,  256, 0, stream>>>(hsb, Wqkab, qk, nullptr, Eb,
                                        dt_bias, A_log_base, A_log_delta);
    mm2<2,16><<<1024, 256, 0, stream>>>(hsb, Wvgb, vb, gbf, nullptr,
                                        nullptr, nullptr, nullptr);

    // chunked recurrence: fine chunks for state (NC=32, fused decay product),
    // coarse chunks for output (16)
    gla_state<<<4096, 256, 0, stream>>>(qk, Eb, vb, Sl, Dc);
    combine<<<dim3(32, 16), 256, 0, stream>>>(Sl, Dc);
    gla_out<<<2048, 256, 0, stream>>>(qk, Eb, vb, Sl, ob);

    // epilogue
    rms_gate<<<NROWS * Hn / 4, 256, 0, stream>>>(ob, gbf, gnw, obf);
    mm2<0,8><<<512, 256, 0, stream>>>(obf, Wob, out, nullptr, nullptr,
                                      nullptr, nullptr, nullptr);
}

// Round 8
// 416.480 us; speedup vs baseline: 1.6299x; 1.6163x over previous
//
#include <hip/hip_runtime.h>
#include <math.h>

#define Bn   4
#define Tn   2048
#define Dn   1024
#define Hn   4
#define DKn  128
#define DVn  256
#define KDn  512
#define VDn  1024
#define NROWS 8192
#define NC   32
#define CLS  64
#define NCO  16
#define CLO  128
#define LOG_T_REF_F 6.2383246250395075f

using bf16x8 = __attribute__((ext_vector_type(8))) short;
using f32x4  = __attribute__((ext_vector_type(4))) float;
using f32x2  = __attribute__((ext_vector_type(2))) float;

__device__ __forceinline__ float softplus_f(float x) {
    return fmaxf(x, 0.0f) + log1pf(expf(-fabsf(x)));
}
__device__ __forceinline__ ushort f2bf(float f) {
    unsigned u = __float_as_uint(f);
    u = (u + 0x7fffu + ((u >> 16) & 1u)) >> 16;
    return (ushort)u;
}
__device__ __forceinline__ void gload16(const void* g, void* l) {
    __builtin_amdgcn_global_load_lds(
        (const __attribute__((address_space(1))) unsigned*)g,
        (__attribute__((address_space(3))) unsigned*)l, 16, 0, 0);
}
// packed full-sum butterfly over each aligned 16-lane group, pure VALU (DPP)
__device__ __forceinline__ f32x2 dpp_red16_x2(f32x2 p) {
    f32x2 t;
#define RSTEP(ctl)                                                                              \
    t.x = __int_as_float(__builtin_amdgcn_mov_dpp(__float_as_int(p.x), ctl, 0xF, 0xF, true));   \
    t.y = __int_as_float(__builtin_amdgcn_mov_dpp(__float_as_int(p.y), ctl, 0xF, 0xF, true));   \
    p = p + t;
    RSTEP(0xB1)   // quad_perm xor1
    RSTEP(0x4E)   // quad_perm xor2
    RSTEP(0x124)  // row_ror:4
    RSTEP(0x128)  // row_ror:8
#undef RSTEP
    return p;
}

// ---------- cast fp32 -> bf16 ----------
__global__ __launch_bounds__(256) void cast_f2b(const float* __restrict__ x,
                                                ushort* __restrict__ y, int n4) {
    int i = blockIdx.x * 256 + threadIdx.x;
    if (i < n4) {
        float4 v = *(const float4*)&x[i * 4];
        ushort4 o;
        o.x = f2bf(v.x); o.y = f2bf(v.y); o.z = f2bf(v.z); o.w = f2bf(v.w);
        *(ushort4*)&y[i * 4] = o;
    }
}

// ---------- bf16 MFMA GEMM (unchanged from R7) ----------
template<int MODE, int NX>
__global__ __launch_bounds__(256) void mm2(const ushort* __restrict__ A,
    const ushort* __restrict__ Bw, float* __restrict__ C,
    ushort* __restrict__ C2, float* __restrict__ Eo,
    const float* __restrict__ dt_bias, const float* __restrict__ A_log_base,
    const float* __restrict__ A_log_delta)
{
    __shared__ __align__(16) ushort As[4][128][8];
    __shared__ __align__(16) ushort Bs[4][128][8];
    const int raw = blockIdx.x;
    const int nwg = NX * 64;
    const int l = (raw & 7) * (nwg >> 3) + (raw >> 3);
    const int bx = l % NX, by = l / NX;
    const int tid = threadIdx.x;
    const int lane = tid & 63, w = tid >> 6;
    const int l15 = lane & 15, lg = lane >> 4;
    const int wr = (w >> 1) << 6, wc = (w & 1) << 6;
    const int row0 = by << 7, col0 = bx << 7;

    const ushort* Ag0 = A  + (size_t)(row0 + lane) * Dn + w * 8;
    const ushort* Ag1 = A  + (size_t)(row0 + 64 + lane) * Dn + w * 8;
    const ushort* Bg0 = Bw + (size_t)(col0 + lane) * Dn + w * 8;
    const ushort* Bg1 = Bw + (size_t)(col0 + 64 + lane) * Dn + w * 8;
    ushort* lA0 = &As[w][0][0];
    ushort* lA1 = &As[w][64][0];
    ushort* lB0 = &Bs[w][0][0];
    ushort* lB1 = &Bs[w][64][0];

    f32x4 acc[4][4];
    #pragma unroll
    for (int m = 0; m < 4; ++m)
        #pragma unroll
        for (int n = 0; n < 4; ++n)
            acc[m][n] = (f32x4){0.f, 0.f, 0.f, 0.f};

    for (int kt = 0; kt < Dn; kt += 32) {
        __syncthreads();
        gload16(Ag0 + kt, lA0);
        gload16(Ag1 + kt, lA1);
        gload16(Bg0 + kt, lB0);
        gload16(Bg1 + kt, lB1);
        __syncthreads();
        bf16x8 af[4], bv[4];
        #pragma unroll
        for (int m = 0; m < 4; ++m) af[m] = *(const bf16x8*)&As[lg][wr + m*16 + l15][0];
        #pragma unroll
        for (int n = 0; n < 4; ++n) bv[n] = *(const bf16x8*)&Bs[lg][wc + n*16 + l15][0];
        #pragma unroll
        for (int m = 0; m < 4; ++m)
            #pragma unroll
            for (int n = 0; n < 4; ++n)
                acc[m][n] = __builtin_amdgcn_mfma_f32_16x16x32_bf16(af[m], bv[n], acc[m][n], 0, 0, 0);
    }

    if (MODE == 1 && col0 >= 1024) {
        const float base_ = A_log_base[0];
        const float s0 = softplus_f(A_log_delta[0]);
        const float s1 = softplus_f(A_log_delta[1]);
        const float s2 = softplus_f(A_log_delta[2]);
        const float c3 = s0 + s1 + s2;
        const float mg = c3 * (1.0f / 3.0f);
        float pf[4][4];
        #pragma unroll
        for (int m = 0; m < 4; ++m) {
            const int row = row0 + wr + m * 16 + lg * 4;
            #pragma unroll
            for (int r = 0; r < 4; ++r) {
                const int t = (row + r) & (Tn - 1);
                pf[m][r] = logf((float)(t + 1));
            }
        }
        #pragma unroll
        for (int n = 0; n < 4; ++n) {
            const int dk = col0 - 1024 + wc + n * 16 + l15;
            const int h = dk >> 7;
            const float cumh = (h == 0) ? 0.f : (h == 1) ? s0 : (h == 2) ? s0 + s1 : c3;
            float alpha = (float)(3 - h) * (1.0f / 3.0f)
                        + (cumh - (float)h * mg) * (1.0f / LOG_T_REF_F);
            alpha = fminf(fmaxf(alpha, 0.0f), 1.0f);
            const float expA = expf(base_ + cumh);
            const float db = dt_bias[dk];
            #pragma unroll
            for (int m = 0; m < 4; ++m) {
                const int row = row0 + wr + m * 16 + lg * 4;
                #pragma unroll
                for (int r = 0; r < 4; ++r) {
                    const float p = expf(-alpha * pf[m][r]);
                    Eo[(size_t)(row + r) * KDn + dk] =
                        expf(-expA * softplus_f(acc[m][n][r] + db) * p);
                }
            }
        }
    } else if (MODE == 2 && col0 >= 1024) {
        #pragma unroll
        for (int m = 0; m < 4; ++m) {
            const int row = row0 + wr + m * 16 + lg * 4;
            #pragma unroll
            for (int n = 0; n < 4; ++n) {
                const int col = col0 - 1024 + wc + n * 16 + l15;
                #pragma unroll
                for (int r = 0; r < 4; ++r)
                    C2[(size_t)(row + r) * 1024 + col] = f2bf(acc[m][n][r]);
            }
        }
    } else {
        const float s = (MODE == 1 && col0 < 512) ? 0.08838834764831845f : 1.0f;
        #pragma unroll
        for (int m = 0; m < 4; ++m) {
            const int row = row0 + wr + m * 16 + lg * 4;
            #pragma unroll
            for (int n = 0; n < 4; ++n) {
                const int col = col0 + wc + n * 16 + l15;
                #pragma unroll
                for (int r = 0; r < 4; ++r)
                    C[(size_t)(row + r) * 1024 + col] = acc[m][n][r] * s;
            }
        }
    }
}

// ---------- chunked GLA recurrence, LDS-staged ----------
// qk: [8192][1024] (q | k). vb: [8192][1024]. E: [8192][512].
// Thread (part, dvi): dk pairs {p4,p4+1},{p4+2,p4+3},{64+p4,+1},{64+p4+2,+3};
// dv = dvb*64 + dvi*4. Inner data comes from LDS tiles of 16 timesteps.

// local states at fine chunks (NC=32 x 64) + fused decay product.
// Grid 2048 = 32c x 16bh x 4dvb, XCD-swizzled.
__global__ __launch_bounds__(256, 6) void gla_state(const float* __restrict__ qk,
    const float* __restrict__ E, const float* __restrict__ vb,
    float* __restrict__ Sl, float* __restrict__ Dc)
{
    __shared__ __align__(16) float sb[5120];   // lk[16][128] | lE[16][128] | lv[16][64]
    float* lk = sb;
    float* lE = sb + 2048;
    float* lv = sb + 4096;

    const int raw = blockIdx.x;
    const int l = (raw & 7) * 256 + (raw >> 3);
    const int dvb = l & 3, bh = (l >> 2) & 15, c = l >> 6;   // c: 0..31
    const int tid = threadIdx.x;
    const int part = tid & 15, dvi = tid >> 4;
    const int w = tid >> 6, lane = tid & 63;
    const int b = bh >> 2, h = bh & 3;
    const int t0 = c * CLS;
    const int dvl = dvi * 4;                  // dv within block slice

    // staging source offsets (per thread)
    const int e4 = w * 64 + lane;             // 0..255
    const int ttq = e4 >> 5, c4q = (e4 & 31) << 2;
    const int ttv = e4 >> 4, c4v = (e4 & 15) << 2;
    int ok = (b * Tn + t0 + ttq) * 1024 + 512 + h * DKn + c4q;
    int oe = (b * Tn + t0 + ttq) * KDn + h * DKn + c4q;
    int ov = (b * Tn + t0 + ttv) * 1024 + h * DVn + dvb * 64 + c4v;
    float* dstq = sb + w * 256;               // wave-uniform 1KB segment (floats)
    float* dstv = lv + w * 256;

    f32x2 S[4][4], P[4];
    #pragma unroll
    for (int i = 0; i < 4; ++i) {
        P[i] = (f32x2){1.f, 1.f};
        #pragma unroll
        for (int j = 0; j < 4; ++j) S[i][j] = (f32x2){0.f, 0.f};
    }

    for (int tile = 0; tile < CLS / 16; ++tile) {
        __syncthreads();
        gload16(qk + ok,        dstq);            // k rows 0-7
        gload16(qk + ok + 8192, dstq + 1024);     // k rows 8-15
        gload16(E + oe,         dstq + 2048);     // E rows 0-7
        gload16(E + oe + 4096,  dstq + 3072);     // E rows 8-15
        gload16(vb + ov,        dstv);            // v rows 0-15
        ok += 16 * 1024; oe += 16 * KDn; ov += 16 * 1024;
        __syncthreads();

        #pragma unroll
        for (int tt = 0; tt < 16; ++tt) {
            float4 kA = *(const float4*)&lk[tt * 128 + part * 4];
            float4 kB = *(const float4*)&lk[tt * 128 + 64 + part * 4];
            float4 eA = *(const float4*)&lE[tt * 128 + part * 4];
            float4 eB = *(const float4*)&lE[tt * 128 + 64 + part * 4];
            float4 vv = *(const float4*)&lv[tt * 64 + dvl];
            f32x2 k2[4] = {{kA.x,kA.y},{kA.z,kA.w},{kB.x,kB.y},{kB.z,kB.w}};
            f32x2 e2[4] = {{eA.x,eA.y},{eA.z,eA.w},{eB.x,eB.y},{eB.z,eB.w}};
            const f32x2 vs[4] = {{vv.x,vv.x},{vv.y,vv.y},{vv.z,vv.z},{vv.w,vv.w}};
            #pragma unroll
            for (int i = 0; i < 4; ++i) {
                P[i] = P[i] * e2[i];
                #pragma unroll
                for (int j = 0; j < 4; ++j)
                    S[i][j] = S[i][j] * e2[i] + k2[i] * vs[j];
            }
        }
    }

    float* sp = Sl + (((size_t)c * 16 + bh) << 15) + dvb * 64 + dvl;
    #pragma unroll
    for (int i = 0; i < 4; ++i) {
        const int dke = (i < 2) ? part * 4 + i * 2 : 64 + part * 4 + (i - 2) * 2;
        *(float4*)&sp[(dke + 0) * DVn] =
            make_float4(S[i][0].x, S[i][1].x, S[i][2].x, S[i][3].x);
        *(float4*)&sp[(dke + 1) * DVn] =
            make_float4(S[i][0].y, S[i][1].y, S[i][2].y, S[i][3].y);
    }
    if (dvb == 0 && dvi == 0) {
        float* dp = Dc + (c * 16 + bh) * DKn;
        #pragma unroll
        for (int i = 0; i < 4; ++i) {
            const int dke = (i < 2) ? part * 4 + i * 2 : 64 + part * 4 + (i - 2) * 2;
            *(float2*)&dp[dke] = make_float2(P[i].x, P[i].y);
        }
    }
}

// sequential chunk combine: overwrite Sl[c] with chunk-c START state
__global__ __launch_bounds__(256) void combine(float* __restrict__ Sl,
                                               const float* __restrict__ Dc) {
    const int bh = blockIdx.y;
    const int e4 = blockIdx.x * 256 + threadIdx.x;
    const int dk = e4 >> 6;
    float4 s = make_float4(0.f, 0.f, 0.f, 0.f);
    #pragma unroll 4
    for (int c = 0; c < NC; ++c) {
        float4* p = (float4*)(Sl + (((size_t)c * 16 + bh) << 15)) + e4;
        float4 local = *p;
        const float d = Dc[(c * 16 + bh) * DKn + dk];
        *p = s;
        s.x = s.x * d + local.x;  s.y = s.y * d + local.y;
        s.z = s.z * d + local.z;  s.w = s.w * d + local.w;
    }
}

// output pass at coarse chunks (NCO=16 x 128), start state = Sl[2*co].
// Grid 1024 = 16co x 16bh x 4dvb, XCD-swizzled, LDS-staged.
__global__ __launch_bounds__(256, 4) void gla_out(const float* __restrict__ qk,
    const float* __restrict__ E, const float* __restrict__ vb,
    const float* __restrict__ Sl, float* __restrict__ o)
{
    __shared__ __align__(16) float sb[7168];  // lq | lk | lE | lv
    float* lq = sb;
    float* lk = sb + 2048;
    float* lE = sb + 4096;
    float* lv = sb + 6144;

    const int raw = blockIdx.x;
    const int l = (raw & 7) * 128 + (raw >> 3);
    const int dvb = l & 3, bh = (l >> 2) & 15, co = l >> 6;  // co: 0..15
    const int tid = threadIdx.x;
    const int part = tid & 15, dvi = tid >> 4;
    const int w = tid >> 6, lane = tid & 63;
    const int b = bh >> 2, h = bh & 3;
    const int t0 = co * CLO;
    const int dvl = dvi * 4;
    const int dv = dvb * 64 + dvl;

    const int e4 = w * 64 + lane;
    const int ttq = e4 >> 5, c4q = (e4 & 31) << 2;
    const int ttv = e4 >> 4, c4v = (e4 & 15) << 2;
    int oq = (b * Tn + t0 + ttq) * 1024 + h * DKn + c4q;
    int oe = (b * Tn + t0 + ttq) * KDn + h * DKn + c4q;
    int ov = (b * Tn + t0 + ttv) * 1024 + h * DVn + dvb * 64 + c4v;
    float* dstq = lq + w * 256;
    float* dstk = lk + w * 256;
    float* dste = lE + w * 256;
    float* dstv = lv + w * 256;

    // start state
    const float* sp = Sl + (((size_t)(2 * co) * 16 + bh) << 15) + dv;
    f32x2 S[4][4];
    #pragma unroll
    for (int i = 0; i < 4; ++i) {
        const int dke = (i < 2) ? part * 4 + i * 2 : 64 + part * 4 + (i - 2) * 2;
        float4 a = *(const float4*)&sp[(dke + 0) * DVn];
        float4 bq = *(const float4*)&sp[(dke + 1) * DVn];
        S[i][0] = (f32x2){a.x, bq.x};
        S[i][1] = (f32x2){a.y, bq.y};
        S[i][2] = (f32x2){a.z, bq.z};
        S[i][3] = (f32x2){a.w, bq.w};
    }

    int oo = (b * Tn + t0) * 1024 + h * DVn + dv;

    for (int tile = 0; tile < CLO / 16; ++tile) {
        __syncthreads();
        gload16(qk + oq,         dstq);           // q rows 0-7
        gload16(qk + oq + 8192,  dstq + 1024);    // q rows 8-15
        gload16(qk + oq + 512,   dstk);           // k rows 0-7
        gload16(qk + oq + 8704,  dstk + 1024);    // k rows 8-15
        gload16(E + oe,          dste);           // E rows 0-7
        gload16(E + oe + 4096,   dste + 1024);    // E rows 8-15
        gload16(vb + ov,         dstv);           // v rows 0-15
        oq += 16 * 1024; oe += 16 * KDn; ov += 16 * 1024;
        __syncthreads();

        #pragma unroll
        for (int tt = 0; tt < 16; ++tt) {
            float4 qA = *(const float4*)&lq[tt * 128 + part * 4];
            float4 qB = *(const float4*)&lq[tt * 128 + 64 + part * 4];
            float4 kA = *(const float4*)&lk[tt * 128 + part * 4];
            float4 kB = *(const float4*)&lk[tt * 128 + 64 + part * 4];
            float4 eA = *(const float4*)&lE[tt * 128 + part * 4];
            float4 eB = *(const float4*)&lE[tt * 128 + 64 + part * 4];
            float4 vv = *(const float4*)&lv[tt * 64 + dvl];
            f32x2 q2[4] = {{qA.x,qA.y},{qA.z,qA.w},{qB.x,qB.y},{qB.z,qB.w}};
            f32x2 k2[4] = {{kA.x,kA.y},{kA.z,kA.w},{kB.x,kB.y},{kB.z,kB.w}};
            f32x2 e2[4] = {{eA.x,eA.y},{eA.z,eA.w},{eB.x,eB.y},{eB.z,eB.w}};
            const f32x2 vs[4] = {{vv.x,vv.x},{vv.y,vv.y},{vv.z,vv.z},{vv.w,vv.w}};
            f32x2 p[4] = {{0.f,0.f},{0.f,0.f},{0.f,0.f},{0.f,0.f}};
            #pragma unroll
            for (int i = 0; i < 4; ++i) {
                #pragma unroll
                for (int j = 0; j < 4; ++j) {
                    S[i][j] = S[i][j] * e2[i] + k2[i] * vs[j];
                    p[j] = p[j] + q2[i] * S[i][j];
                }
            }
            f32x2 pp01 = (f32x2){p[0].x + p[0].y, p[1].x + p[1].y};
            f32x2 pp23 = (f32x2){p[2].x + p[2].y, p[3].x + p[3].y};
            pp01 = dpp_red16_x2(pp01);
            pp23 = dpp_red16_x2(pp23);
            if (part == 0)
                *(float4*)(o + oo) = make_float4(pp01.x, pp01.y, pp23.x, pp23.y);
            oo += 1024;
        }
    }
}

// ---------- RMSNorm + swish gate (g in bf16) -> bf16 ----------
__global__ __launch_bounds__(256) void rms_gate(const float* __restrict__ o,
    const ushort* __restrict__ gbf, const float* __restrict__ wt,
    ushort* __restrict__ obf)
{
    const int tid = threadIdx.x;
    const int w = tid >> 6, lane = tid & 63;
    const int row = blockIdx.x * 4 + w;
    const int n = row >> 2, h = row & 3;
    const size_t ob_base = (size_t)n * VDn + h * DVn + lane * 4;

    float4 o4 = *(const float4*)&o[ob_base];
    float ss = o4.x*o4.x + o4.y*o4.y + o4.z*o4.z + o4.w*o4.w;
    #pragma unroll
    for (int m = 1; m < 64; m <<= 1) ss += __shfl_xor(ss, m);
    const float r = rsqrtf(ss * (1.0f / DVn) + 1e-5f);

    ushort4 gu = *(const ushort4*)&gbf[ob_base];
    float gx = __uint_as_float((unsigned)gu.x << 16);
    float gy = __uint_as_float((unsigned)gu.y << 16);
    float gz = __uint_as_float((unsigned)gu.z << 16);
    float gw = __uint_as_float((unsigned)gu.w << 16);
    float4 w4 = *(const float4*)&wt[h * DVn + lane * 4];
    ushort4 u;
    u.x = f2bf(o4.x * r * w4.x * (gx / (1.0f + expf(-gx))));
    u.y = f2bf(o4.y * r * w4.y * (gy / (1.0f + expf(-gy))));
    u.z = f2bf(o4.z * r * w4.z * (gz / (1.0f + expf(-gz))));
    u.w = f2bf(o4.w * r * w4.w * (gw / (1.0f + expf(-gw))));
    *(ushort4*)&obf[ob_base] = u;
}

extern "C" void kernel_launch(void* const* d_in, const int* in_sizes, int n_in,
                              void* d_out, int out_size, void* d_ws, size_t ws_size,
                              hipStream_t stream) {
    const float* hs          = (const float*)d_in[0];
    const float* Wq          = (const float*)d_in[1];
    const float* Wk          = (const float*)d_in[2];
    const float* Wv          = (const float*)d_in[3];
    const float* Wg          = (const float*)d_in[4];
    const float* Wa          = (const float*)d_in[5];
    const float* Wo          = (const float*)d_in[6];
    const float* A_log_base  = (const float*)d_in[7];
    const float* A_log_delta = (const float*)d_in[8];
    const float* dt_bias     = (const float*)d_in[9];
    const float* gnw         = (const float*)d_in[10];
    float* out = (float*)d_out;

    char* ws = (char*)d_ws;
    float*  qk   = (float*)(ws);                           // 32MB [8192][1024] q|k
    float*  vb   = (float*)(ws + ((size_t)32  << 20));     // 32MB [8192][1024] v
    float*  Eb   = (float*)(ws + ((size_t)64  << 20));     // 16MB [8192][512]
    float*  Sl   = (float*)(ws + ((size_t)80  << 20));     // 64MB [32][16][128][256]
    float*  ob   = (float*)(ws + ((size_t)144 << 20));     // 32MB [8192][1024]
    ushort* hsb  = (ushort*)(ws + ((size_t)144 << 20));    // 16MB overlay on ob
    ushort* gbf  = (ushort*)(ws + ((size_t)176 << 20));    // 16MB [8192][1024] g bf16
    ushort* Wqkab= (ushort*)(ws + ((size_t)192 << 20));    //  3MB
    ushort* Wvgb = (ushort*)(ws + ((size_t)195 << 20));    //  4MB
    ushort* Wob  = (ushort*)(ws + ((size_t)199 << 20));    //  2MB
    float*  Dc   = (float*)(ws + ((size_t)201 << 20));     // 256KB
    ushort* obf  = (ushort*)qk;                            // reuse qk after gla_out

    // casts
    cast_f2b<<<NROWS * Dn / 4 / 256, 256, 0, stream>>>(hs, hsb, NROWS * Dn / 4);
    cast_f2b<<<512,  256, 0, stream>>>(Wq, Wqkab,              KDn * Dn / 4);
    cast_f2b<<<512,  256, 0, stream>>>(Wk, Wqkab + KDn * Dn,   KDn * Dn / 4);
    cast_f2b<<<512,  256, 0, stream>>>(Wa, Wqkab + 2*KDn * Dn, KDn * Dn / 4);
    cast_f2b<<<1024, 256, 0, stream>>>(Wv, Wvgb,               VDn * Dn / 4);
    cast_f2b<<<1024, 256, 0, stream>>>(Wg, Wvgb + VDn * Dn,    VDn * Dn / 4);
    cast_f2b<<<1024, 256, 0, stream>>>(Wo, Wob,                VDn * Dn / 4);

    // projections
    mm2<1,12><<<768,  256, 0, stream>>>(hsb, Wqkab, qk, nullptr, Eb,
                                        dt_bias, A_log_base, A_log_delta);
    mm2<2,16><<<1024, 256, 0, stream>>>(hsb, Wvgb, vb, gbf, nullptr,
                                        nullptr, nullptr, nullptr);

    // chunked recurrence (LDS-staged scans)
    gla_state<<<2048, 256, 0, stream>>>(qk, Eb, vb, Sl, Dc);
    combine<<<dim3(32, 16), 256, 0, stream>>>(Sl, Dc);
    gla_out<<<1024, 256, 0, stream>>>(qk, Eb, vb, Sl, ob);

    // epilogue
    rms_gate<<<NROWS * Hn / 4, 256, 0, stream>>>(ob, gbf, gnw, obf);
    mm2<0,8><<<512, 256, 0, stream>>>(obf, Wob, out, nullptr, nullptr,
                                      nullptr, nullptr, nullptr);
}

// Round 9
// 381.683 us; speedup vs baseline: 1.7785x; 1.0912x over previous
//
#include <hip/hip_runtime.h>
#include <math.h>

#define Bn   4
#define Tn   2048
#define Dn   1024
#define Hn   4
#define DKn  128
#define DVn  256
#define KDn  512
#define VDn  1024
#define NROWS 8192
#define NCC  16
#define CLO  128
#define LOG_T_REF_F 6.2383246250395075f

using bf16x8 = __attribute__((ext_vector_type(8))) short;
using f32x4  = __attribute__((ext_vector_type(4))) float;
using f32x2  = __attribute__((ext_vector_type(2))) float;

__device__ __forceinline__ float softplus_f(float x) {
    return fmaxf(x, 0.0f) + log1pf(expf(-fabsf(x)));
}
__device__ __forceinline__ ushort f2bf(float f) {
    unsigned u = __float_as_uint(f);
    u = (u + 0x7fffu + ((u >> 16) & 1u)) >> 16;
    return (ushort)u;
}
__device__ __forceinline__ void gload16(const void* g, void* l) {
    __builtin_amdgcn_global_load_lds(
        (const __attribute__((address_space(1))) unsigned*)g,
        (__attribute__((address_space(3))) unsigned*)l, 16, 0, 0);
}
// packed full-sum butterfly over each aligned 16-lane group, pure VALU (DPP)
__device__ __forceinline__ f32x2 dpp_red16_x2(f32x2 p) {
    f32x2 t;
#define RSTEP(ctl)                                                                              \
    t.x = __int_as_float(__builtin_amdgcn_mov_dpp(__float_as_int(p.x), ctl, 0xF, 0xF, true));   \
    t.y = __int_as_float(__builtin_amdgcn_mov_dpp(__float_as_int(p.y), ctl, 0xF, 0xF, true));   \
    p = p + t;
    RSTEP(0xB1)   // quad_perm xor1
    RSTEP(0x4E)   // quad_perm xor2
    RSTEP(0x124)  // row_ror:4
    RSTEP(0x128)  // row_ror:8
#undef RSTEP
    return p;
}

// ---------- cast fp32 -> bf16 ----------
__global__ __launch_bounds__(256) void cast_f2b(const float* __restrict__ x,
                                                ushort* __restrict__ y, int n4) {
    int i = blockIdx.x * 256 + threadIdx.x;
    if (i < n4) {
        float4 v = *(const float4*)&x[i * 4];
        ushort4 o;
        o.x = f2bf(v.x); o.y = f2bf(v.y); o.z = f2bf(v.z); o.w = f2bf(v.w);
        *(ushort4*)&y[i * 4] = o;
    }
}

// ---------- bf16 MFMA GEMM (unchanged from R8) ----------
template<int MODE, int NX>
__global__ __launch_bounds__(256) void mm2(const ushort* __restrict__ A,
    const ushort* __restrict__ Bw, float* __restrict__ C,
    ushort* __restrict__ C2, float* __restrict__ Eo,
    const float* __restrict__ dt_bias, const float* __restrict__ A_log_base,
    const float* __restrict__ A_log_delta)
{
    __shared__ __align__(16) ushort As[4][128][8];
    __shared__ __align__(16) ushort Bs[4][128][8];
    const int raw = blockIdx.x;
    const int nwg = NX * 64;
    const int l = (raw & 7) * (nwg >> 3) + (raw >> 3);
    const int bx = l % NX, by = l / NX;
    const int tid = threadIdx.x;
    const int lane = tid & 63, w = tid >> 6;
    const int l15 = lane & 15, lg = lane >> 4;
    const int wr = (w >> 1) << 6, wc = (w & 1) << 6;
    const int row0 = by << 7, col0 = bx << 7;

    const ushort* Ag0 = A  + (size_t)(row0 + lane) * Dn + w * 8;
    const ushort* Ag1 = A  + (size_t)(row0 + 64 + lane) * Dn + w * 8;
    const ushort* Bg0 = Bw + (size_t)(col0 + lane) * Dn + w * 8;
    const ushort* Bg1 = Bw + (size_t)(col0 + 64 + lane) * Dn + w * 8;
    ushort* lA0 = &As[w][0][0];
    ushort* lA1 = &As[w][64][0];
    ushort* lB0 = &Bs[w][0][0];
    ushort* lB1 = &Bs[w][64][0];

    f32x4 acc[4][4];
    #pragma unroll
    for (int m = 0; m < 4; ++m)
        #pragma unroll
        for (int n = 0; n < 4; ++n)
            acc[m][n] = (f32x4){0.f, 0.f, 0.f, 0.f};

    for (int kt = 0; kt < Dn; kt += 32) {
        __syncthreads();
        gload16(Ag0 + kt, lA0);
        gload16(Ag1 + kt, lA1);
        gload16(Bg0 + kt, lB0);
        gload16(Bg1 + kt, lB1);
        __syncthreads();
        bf16x8 af[4], bv[4];
        #pragma unroll
        for (int m = 0; m < 4; ++m) af[m] = *(const bf16x8*)&As[lg][wr + m*16 + l15][0];
        #pragma unroll
        for (int n = 0; n < 4; ++n) bv[n] = *(const bf16x8*)&Bs[lg][wc + n*16 + l15][0];
        #pragma unroll
        for (int m = 0; m < 4; ++m)
            #pragma unroll
            for (int n = 0; n < 4; ++n)
                acc[m][n] = __builtin_amdgcn_mfma_f32_16x16x32_bf16(af[m], bv[n], acc[m][n], 0, 0, 0);
    }

    if (MODE == 1 && col0 >= 1024) {
        const float base_ = A_log_base[0];
        const float s0 = softplus_f(A_log_delta[0]);
        const float s1 = softplus_f(A_log_delta[1]);
        const float s2 = softplus_f(A_log_delta[2]);
        const float c3 = s0 + s1 + s2;
        const float mg = c3 * (1.0f / 3.0f);
        float pf[4][4];
        #pragma unroll
        for (int m = 0; m < 4; ++m) {
            const int row = row0 + wr + m * 16 + lg * 4;
            #pragma unroll
            for (int r = 0; r < 4; ++r) {
                const int t = (row + r) & (Tn - 1);
                pf[m][r] = logf((float)(t + 1));
            }
        }
        #pragma unroll
        for (int n = 0; n < 4; ++n) {
            const int dk = col0 - 1024 + wc + n * 16 + l15;
            const int h = dk >> 7;
            const float cumh = (h == 0) ? 0.f : (h == 1) ? s0 : (h == 2) ? s0 + s1 : c3;
            float alpha = (float)(3 - h) * (1.0f / 3.0f)
                        + (cumh - (float)h * mg) * (1.0f / LOG_T_REF_F);
            alpha = fminf(fmaxf(alpha, 0.0f), 1.0f);
            const float expA = expf(base_ + cumh);
            const float db = dt_bias[dk];
            #pragma unroll
            for (int m = 0; m < 4; ++m) {
                const int row = row0 + wr + m * 16 + lg * 4;
                #pragma unroll
                for (int r = 0; r < 4; ++r) {
                    const float p = expf(-alpha * pf[m][r]);
                    Eo[(size_t)(row + r) * KDn + dk] =
                        expf(-expA * softplus_f(acc[m][n][r] + db) * p);
                }
            }
        }
    } else if (MODE == 2 && col0 >= 1024) {
        #pragma unroll
        for (int m = 0; m < 4; ++m) {
            const int row = row0 + wr + m * 16 + lg * 4;
            #pragma unroll
            for (int n = 0; n < 4; ++n) {
                const int col = col0 - 1024 + wc + n * 16 + l15;
                #pragma unroll
                for (int r = 0; r < 4; ++r)
                    C2[(size_t)(row + r) * 1024 + col] = f2bf(acc[m][n][r]);
            }
        }
    } else {
        const float s = (MODE == 1 && col0 < 512) ? 0.08838834764831845f : 1.0f;
        #pragma unroll
        for (int m = 0; m < 4; ++m) {
            const int row = row0 + wr + m * 16 + lg * 4;
            #pragma unroll
            for (int n = 0; n < 4; ++n) {
                const int col = col0 + wc + n * 16 + l15;
                #pragma unroll
                for (int r = 0; r < 4; ++r)
                    C[(size_t)(row + r) * 1024 + col] = acc[m][n][r] * s;
            }
        }
    }
}

// ---------- single-pass chunked GLA scan (LDS-staged) ----------
// Per coarse chunk of 128: scan from ZERO state. Writes o_local, S_local[co],
// Dc (chunk decay prod), and q~ = q * Lam (cumulative in-chunk decay).
// Grid 1024 = 16co x 16bh x 4dvb, XCD-swizzled. Thread (part,dvi): dk pairs
// {p4,p4+1},{p4+2,p4+3},{64+p4,+1},{64+p4+2,+3}; dv = dvb*64 + dvi*4.
__global__ __launch_bounds__(256, 4) void gla_scan(const float* __restrict__ qk,
    const float* __restrict__ E, const float* __restrict__ vb,
    float* __restrict__ o, float* __restrict__ Sl, float* __restrict__ qt,
    float* __restrict__ Dc)
{
    __shared__ __align__(16) float sb[7168];  // lq | lk | lE | lv
    float* lq = sb;
    float* lk = sb + 2048;
    float* lE = sb + 4096;
    float* lv = sb + 6144;

    const int raw = blockIdx.x;
    const int l = (raw & 7) * 128 + (raw >> 3);
    const int dvb = l & 3, bh = (l >> 2) & 15, co = l >> 6;  // co: 0..15
    const int tid = threadIdx.x;
    const int part = tid & 15, dvi = tid >> 4;
    const int w = tid >> 6, lane = tid & 63;
    const int b = bh >> 2, h = bh & 3;
    const int t0 = co * CLO;
    const int dvl = dvi * 4;
    const int dv = dvb * 64 + dvl;

    const int e4 = w * 64 + lane;
    const int ttq = e4 >> 5, c4q = (e4 & 31) << 2;
    const int ttv = e4 >> 4, c4v = (e4 & 15) << 2;
    int oq = (b * Tn + t0 + ttq) * 1024 + h * DKn + c4q;
    int oe = (b * Tn + t0 + ttq) * KDn + h * DKn + c4q;
    int ov = (b * Tn + t0 + ttv) * 1024 + h * DVn + dvb * 64 + c4v;
    float* dstq = lq + w * 256;
    float* dstk = lk + w * 256;
    float* dste = lE + w * 256;
    float* dstv = lv + w * 256;

    f32x2 S[4][4], Lam[4];
    #pragma unroll
    for (int i = 0; i < 4; ++i) {
        Lam[i] = (f32x2){1.f, 1.f};
        #pragma unroll
        for (int j = 0; j < 4; ++j) S[i][j] = (f32x2){0.f, 0.f};
    }

    int oo  = (b * Tn + t0) * 1024 + h * DVn + dv;
    int qo2 = (b * Tn + t0) * 512 + h * DKn + part * 4;

    for (int tile = 0; tile < CLO / 16; ++tile) {
        __syncthreads();
        gload16(qk + oq,         dstq);           // q rows 0-7
        gload16(qk + oq + 8192,  dstq + 1024);    // q rows 8-15
        gload16(qk + oq + 512,   dstk);           // k rows 0-7
        gload16(qk + oq + 8704,  dstk + 1024);    // k rows 8-15
        gload16(E + oe,          dste);           // E rows 0-7
        gload16(E + oe + 4096,   dste + 1024);    // E rows 8-15
        gload16(vb + ov,         dstv);           // v rows 0-15
        oq += 16 * 1024; oe += 16 * KDn; ov += 16 * 1024;
        __syncthreads();

        #pragma unroll
        for (int tt = 0; tt < 16; ++tt) {
            float4 qA = *(const float4*)&lq[tt * 128 + part * 4];
            float4 qB = *(const float4*)&lq[tt * 128 + 64 + part * 4];
            float4 kA = *(const float4*)&lk[tt * 128 + part * 4];
            float4 kB = *(const float4*)&lk[tt * 128 + 64 + part * 4];
            float4 eA = *(const float4*)&lE[tt * 128 + part * 4];
            float4 eB = *(const float4*)&lE[tt * 128 + 64 + part * 4];
            float4 vv = *(const float4*)&lv[tt * 64 + dvl];
            f32x2 q2[4] = {{qA.x,qA.y},{qA.z,qA.w},{qB.x,qB.y},{qB.z,qB.w}};
            f32x2 k2[4] = {{kA.x,kA.y},{kA.z,kA.w},{kB.x,kB.y},{kB.z,kB.w}};
            f32x2 e2[4] = {{eA.x,eA.y},{eA.z,eA.w},{eB.x,eB.y},{eB.z,eB.w}};
            const f32x2 vs[4] = {{vv.x,vv.x},{vv.y,vv.y},{vv.z,vv.z},{vv.w,vv.w}};
            f32x2 p[4] = {{0.f,0.f},{0.f,0.f},{0.f,0.f},{0.f,0.f}};
            #pragma unroll
            for (int i = 0; i < 4; ++i) {
                Lam[i] = Lam[i] * e2[i];
                #pragma unroll
                for (int j = 0; j < 4; ++j) {
                    S[i][j] = S[i][j] * e2[i] + k2[i] * vs[j];
                    p[j] = p[j] + q2[i] * S[i][j];
                }
            }
            f32x2 pp01 = (f32x2){p[0].x + p[0].y, p[1].x + p[1].y};
            f32x2 pp23 = (f32x2){p[2].x + p[2].y, p[3].x + p[3].y};
            pp01 = dpp_red16_x2(pp01);
            pp23 = dpp_red16_x2(pp23);
            if (part == 0)
                *(float4*)(o + oo) = make_float4(pp01.x, pp01.y, pp23.x, pp23.y);
            oo += 1024;
            if (dvb == 0 && tid < 16) {  // q~ = q * Lam (one writer per dk)
                f32x2 a0 = q2[0] * Lam[0], a1 = q2[1] * Lam[1];
                f32x2 a2 = q2[2] * Lam[2], a3 = q2[3] * Lam[3];
                *(float4*)(qt + qo2)      = make_float4(a0.x, a0.y, a1.x, a1.y);
                *(float4*)(qt + qo2 + 64) = make_float4(a2.x, a2.y, a3.x, a3.y);
            }
            qo2 += 512;
        }
    }

    // local end-state writeback
    float* sp = Sl + (((size_t)co * 16 + bh) << 15) + dv;
    #pragma unroll
    for (int i = 0; i < 4; ++i) {
        const int dke = (i < 2) ? part * 4 + i * 2 : 64 + part * 4 + (i - 2) * 2;
        *(float4*)&sp[(size_t)(dke + 0) * DVn] =
            make_float4(S[i][0].x, S[i][1].x, S[i][2].x, S[i][3].x);
        *(float4*)&sp[(size_t)(dke + 1) * DVn] =
            make_float4(S[i][0].y, S[i][1].y, S[i][2].y, S[i][3].y);
    }
    if (dvb == 0 && dvi == 0) {
        float* dp = Dc + (co * 16 + bh) * DKn;
        #pragma unroll
        for (int i = 0; i < 4; ++i) {
            const int dke = (i < 2) ? part * 4 + i * 2 : 64 + part * 4 + (i - 2) * 2;
            *(float2*)&dp[dke] = make_float2(Lam[i].x, Lam[i].y);
        }
    }
}

// sequential chunk combine (16 coarse chunks): overwrite Sl[c] with START state
__global__ __launch_bounds__(256) void combine(float* __restrict__ Sl,
                                               const float* __restrict__ Dc) {
    const int bh = blockIdx.y;
    const int e4 = blockIdx.x * 256 + threadIdx.x;
    const int dk = e4 >> 6;
    float4 s = make_float4(0.f, 0.f, 0.f, 0.f);
    #pragma unroll 4
    for (int c = 0; c < NCC; ++c) {
        float4* p = (float4*)(Sl + (((size_t)c * 16 + bh) << 15)) + e4;
        float4 local = *p;
        const float d = Dc[(c * 16 + bh) * DKn + dk];
        *p = s;
        s.x = s.x * d + local.x;  s.y = s.y * d + local.y;
        s.z = s.z * d + local.z;  s.w = s.w * d + local.w;
    }
}

// inter-chunk correction: o[t][dv] += sum_dk q~[t][dk] * S_start[dk][dv]
// fp32 tiled GEMM, per block: 128t x 64dv, K=128. Grid 1024 = 16co x 16bh x 4dvt.
__global__ __launch_bounds__(256, 4) void fixup(const float* __restrict__ qt,
    const float* __restrict__ Sl, float* __restrict__ o)
{
    __shared__ __align__(16) float Aq[16][128];  // [kk][t]
    __shared__ __align__(16) float Bs[16][64];   // [kk][dv]
    const int raw = blockIdx.x;
    const int l = (raw & 7) * 128 + (raw >> 3);
    const int dvt = l & 3, bh = (l >> 2) & 15, co = l >> 6;
    const int b = bh >> 2, h = bh & 3;
    const int tid = threadIdx.x;
    const int tx = tid & 15, ty = tid >> 4;
    const int t0 = co * CLO;
    const int dv0 = dvt * 64;

    const float* qbase = qt + (size_t)(b * Tn + t0) * 512 + h * DKn;
    const float* sbase = Sl + (((size_t)co * 16 + bh) << 15) + dv0;

    float acc[8][4] = {};
    for (int k0 = 0; k0 < DKn; k0 += 16) {
        __syncthreads();
        #pragma unroll
        for (int s = 0; s < 2; ++s) {
            const int f = tid + s * 256;
            const int t = f >> 2, kk4 = (f & 3) << 2;
            float4 a = *(const float4*)&qbase[(size_t)t * 512 + k0 + kk4];
            Aq[kk4 + 0][t] = a.x; Aq[kk4 + 1][t] = a.y;
            Aq[kk4 + 2][t] = a.z; Aq[kk4 + 3][t] = a.w;
        }
        {
            const int dk = tid >> 4, dvq = (tid & 15) << 2;
            *(float4*)&Bs[dk][dvq] = *(const float4*)&sbase[(size_t)(k0 + dk) * DVn + dvq];
        }
        __syncthreads();
        #pragma unroll
        for (int kk = 0; kk < 16; ++kk) {
            float4 a0 = *(const float4*)&Aq[kk][ty * 8];
            float4 a1 = *(const float4*)&Aq[kk][ty * 8 + 4];
            float4 bv = *(const float4*)&Bs[kk][tx * 4];
            float ar[8] = {a0.x,a0.y,a0.z,a0.w,a1.x,a1.y,a1.z,a1.w};
            float br[4] = {bv.x,bv.y,bv.z,bv.w};
            #pragma unroll
            for (int i = 0; i < 8; ++i)
                #pragma unroll
                for (int j = 0; j < 4; ++j)
                    acc[i][j] += ar[i] * br[j];
        }
    }
    float* ob = o + (size_t)(b * Tn + t0) * 1024 + h * DVn + dv0;
    #pragma unroll
    for (int i = 0; i < 8; ++i) {
        float* row = ob + (size_t)(ty * 8 + i) * 1024 + tx * 4;
        float4 c = *(float4*)row;
        c.x += acc[i][0]; c.y += acc[i][1];
        c.z += acc[i][2]; c.w += acc[i][3];
        *(float4*)row = c;
    }
}

// ---------- RMSNorm + swish gate (g in bf16) -> bf16 ----------
__global__ __launch_bounds__(256) void rms_gate(const float* __restrict__ o,
    const ushort* __restrict__ gbf, const float* __restrict__ wt,
    ushort* __restrict__ obf)
{
    const int tid = threadIdx.x;
    const int w = tid >> 6, lane = tid & 63;
    const int row = blockIdx.x * 4 + w;
    const int n = row >> 2, h = row & 3;
    const size_t ob_base = (size_t)n * VDn + h * DVn + lane * 4;

    float4 o4 = *(const float4*)&o[ob_base];
    float ss = o4.x*o4.x + o4.y*o4.y + o4.z*o4.z + o4.w*o4.w;
    #pragma unroll
    for (int m = 1; m < 64; m <<= 1) ss += __shfl_xor(ss, m);
    const float r = rsqrtf(ss * (1.0f / DVn) + 1e-5f);

    ushort4 gu = *(const ushort4*)&gbf[ob_base];
    float gx = __uint_as_float((unsigned)gu.x << 16);
    float gy = __uint_as_float((unsigned)gu.y << 16);
    float gz = __uint_as_float((unsigned)gu.z << 16);
    float gw = __uint_as_float((unsigned)gu.w << 16);
    float4 w4 = *(const float4*)&wt[h * DVn + lane * 4];
    ushort4 u;
    u.x = f2bf(o4.x * r * w4.x * (gx / (1.0f + expf(-gx))));
    u.y = f2bf(o4.y * r * w4.y * (gy / (1.0f + expf(-gy))));
    u.z = f2bf(o4.z * r * w4.z * (gz / (1.0f + expf(-gz))));
    u.w = f2bf(o4.w * r * w4.w * (gw / (1.0f + expf(-gw))));
    *(ushort4*)&obf[ob_base] = u;
}

extern "C" void kernel_launch(void* const* d_in, const int* in_sizes, int n_in,
                              void* d_out, int out_size, void* d_ws, size_t ws_size,
                              hipStream_t stream) {
    const float* hs          = (const float*)d_in[0];
    const float* Wq          = (const float*)d_in[1];
    const float* Wk          = (const float*)d_in[2];
    const float* Wv          = (const float*)d_in[3];
    const float* Wg          = (const float*)d_in[4];
    const float* Wa          = (const float*)d_in[5];
    const float* Wo          = (const float*)d_in[6];
    const float* A_log_base  = (const float*)d_in[7];
    const float* A_log_delta = (const float*)d_in[8];
    const float* dt_bias     = (const float*)d_in[9];
    const float* gnw         = (const float*)d_in[10];
    float* out = (float*)d_out;

    char* ws = (char*)d_ws;
    float*  qk   = (float*)(ws);                           // 32MB [8192][1024] q|k
    float*  vb   = (float*)(ws + ((size_t)32  << 20));     // 32MB [8192][1024] v
    float*  Eb   = (float*)(ws + ((size_t)64  << 20));     // 16MB [8192][512]
    float*  Sl   = (float*)(ws + ((size_t)80  << 20));     // 32MB [16][16][128][256]
    float*  qtb  = (float*)(ws + ((size_t)112 << 20));     // 16MB [8192][512] q~
    float*  ob   = (float*)(ws + ((size_t)144 << 20));     // 32MB [8192][1024]
    ushort* hsb  = (ushort*)(ws + ((size_t)144 << 20));    // 16MB overlay on ob
    ushort* gbf  = (ushort*)(ws + ((size_t)176 << 20));    // 16MB [8192][1024] g bf16
    ushort* Wqkab= (ushort*)(ws + ((size_t)192 << 20));    //  3MB
    ushort* Wvgb = (ushort*)(ws + ((size_t)195 << 20));    //  4MB
    ushort* Wob  = (ushort*)(ws + ((size_t)199 << 20));    //  2MB
    float*  Dc   = (float*)(ws + ((size_t)201 << 20));     // 128KB [16][16][128]
    ushort* obf  = (ushort*)qk;                            // reuse qk after gla_scan

    // casts
    cast_f2b<<<NROWS * Dn / 4 / 256, 256, 0, stream>>>(hs, hsb, NROWS * Dn / 4);
    cast_f2b<<<512,  256, 0, stream>>>(Wq, Wqkab,              KDn * Dn / 4);
    cast_f2b<<<512,  256, 0, stream>>>(Wk, Wqkab + KDn * Dn,   KDn * Dn / 4);
    cast_f2b<<<512,  256, 0, stream>>>(Wa, Wqkab + 2*KDn * Dn, KDn * Dn / 4);
    cast_f2b<<<1024, 256, 0, stream>>>(Wv, Wvgb,               VDn * Dn / 4);
    cast_f2b<<<1024, 256, 0, stream>>>(Wg, Wvgb + VDn * Dn,    VDn * Dn / 4);
    cast_f2b<<<1024, 256, 0, stream>>>(Wo, Wob,                VDn * Dn / 4);

    // projections
    mm2<1,12><<<768,  256, 0, stream>>>(hsb, Wqkab, qk, nullptr, Eb,
                                        dt_bias, A_log_base, A_log_delta);
    mm2<2,16><<<1024, 256, 0, stream>>>(hsb, Wvgb, vb, gbf, nullptr,
                                        nullptr, nullptr, nullptr);

    // single-pass scan + coarse combine + inter-chunk fixup
    gla_scan<<<1024, 256, 0, stream>>>(qk, Eb, vb, ob, Sl, qtb, Dc);
    combine<<<dim3(32, 16), 256, 0, stream>>>(Sl, Dc);
    fixup<<<1024, 256, 0, stream>>>(qtb, Sl, ob);

    // epilogue
    rms_gate<<<NROWS * Hn / 4, 256, 0, stream>>>(ob, gbf, gnw, obf);
    mm2<0,8><<<512, 256, 0, stream>>>(obf, Wob, out, nullptr, nullptr,
                                      nullptr, nullptr, nullptr);
}